// Round 5
// baseline (50497.879 us; speedup 1.0000x reference)
//
#include <hip/hip_runtime.h>
#include <hip/hip_bf16.h>
#include <math.h>

#define T_LEN 128
#define BATCH 64
#define IND   512
#define HDIM  256
#define NS    8
#define H4    1024
#define NTHR  512
#define ROWS  8

typedef unsigned long long ull;
typedef unsigned int uint;
typedef unsigned short ushort;

// ---- LLC-coherent accessors: agent-scope relaxed atomics ----
__device__ __forceinline__ float gload(const float* p) {
  return __hip_atomic_load(p, __ATOMIC_RELAXED, __HIP_MEMORY_SCOPE_AGENT);
}
__device__ __forceinline__ float2 gload2(const float* p) {
  ull v = __hip_atomic_load((const ull*)p, __ATOMIC_RELAXED, __HIP_MEMORY_SCOPE_AGENT);
  return __builtin_bit_cast(float2, v);
}
__device__ __forceinline__ void gstore(float* p, float v) {
  __hip_atomic_store(p, v, __ATOMIC_RELAXED, __HIP_MEMORY_SCOPE_AGENT);
}
__device__ __forceinline__ void gstore2(float* p, float a, float b) {
  float2 t = make_float2(a, b);
  __hip_atomic_store((ull*)p, __builtin_bit_cast(ull, t), __ATOMIC_RELAXED, __HIP_MEMORY_SCOPE_AGENT);
}

__device__ __forceinline__ float2 bf2(uint u) {
  return make_float2(__uint_as_float(u << 16), __uint_as_float(u & 0xffff0000u));
}

// ---- swizzled LDS index helpers (conflict-free bank-quad spread) ----
__device__ __forceinline__ int AHM(int r, int k) {  // A for Z1: [8][512], fp32
  return r * 512 + (k & 256) + ((((k >> 2) + r) & 63) << 2) + (k & 3);
}
__device__ __forceinline__ int AZi(int r, int k) {  // A for Z2: [8][1024], fp32
  return r * 1024 + ((((k >> 2) + r) & 255) << 2) + (k & 3);
}
__device__ __forceinline__ int W1I(int c, int k) {  // W1 slice: [32][512], bf16
  return c * 512 + ((((k >> 3) + (c >> 2)) & 63) << 3) + (k & 7);
}
__device__ __forceinline__ int W2I(int c, int k) {  // W2 slice: [32][1024], bf16
  return c * 1024 + ((((k >> 3) + (c >> 2)) & 127) << 3) + (k & 7);
}
__device__ __forceinline__ int REDI(int w, int r, int cl) {
  return w * 256 + r * 32 + ((cl + r * 4) & 31);
}

// ---- per-cluster barrier: 32 blocks, flags PACKED into 2 cache lines.
// Lane i polls flag i and exits when satisfied (poll traffic shrinks as
// blocks arrive). Round-4 lesson: 16-int-strided flags = 32 lines/poll-iter
// = 27+ GB of fabric garbage. Packed = 2 lines/iter. ----
__device__ __forceinline__ void cbar(int* flags, int cg, int ph) {
  asm volatile("s_waitcnt vmcnt(0)" ::: "memory");
  __syncthreads();
  if (threadIdx.x == 0)
    __hip_atomic_store(flags + cg, ph, __ATOMIC_RELAXED, __HIP_MEMORY_SCOPE_AGENT);
  if (threadIdx.x < 32) {
    while (__hip_atomic_load(flags + threadIdx.x, __ATOMIC_RELAXED, __HIP_MEMORY_SCOPE_AGENT) < ph)
      __builtin_amdgcn_s_sleep(2);
  }
  __syncthreads();
}

extern "C" __global__ void init_ctrl(int* ctrl) {
  int t = blockIdx.x * blockDim.x + threadIdx.x;
  if (t < 4096) ctrl[t] = 0;
}

// ---------------- Xp = tanh(LN(X @ W_proj + b)) ----------------
extern "C" __global__ __launch_bounds__(256) void xp_kernel(
    const float* __restrict__ X, const float* __restrict__ Wp, const float* __restrict__ bp,
    const float* __restrict__ lns, const float* __restrict__ lnb, float* __restrict__ out_xp)
{
  __shared__ float Xs[8 * IND];
  __shared__ float Ys[8 * HDIM];
  const int tid = threadIdx.x;
  const size_t base = (size_t)blockIdx.x * 8;
  const float* Xb = X + base * IND;
  for (int e = tid; e < 8 * IND / 4; e += 256) ((float4*)Xs)[e] = ((const float4*)Xb)[e];
  __syncthreads();
  float acc[8];
#pragma unroll
  for (int r = 0; r < 8; ++r) acc[r] = 0.f;
  for (int k = 0; k < IND; ++k) {
    float wv = Wp[k * HDIM + tid];
#pragma unroll
    for (int r = 0; r < 8; ++r) acc[r] += Xs[r * IND + k] * wv;
  }
  float bpv = bp[tid];
#pragma unroll
  for (int r = 0; r < 8; ++r) Ys[r * HDIM + tid] = acc[r] + bpv;
  __syncthreads();
  int w = tid >> 6, lane = tid & 63;
  for (int rr = 0; rr < 2; ++rr) {
    int r = w * 2 + rr;
    float v[4]; float s1 = 0.f, s2 = 0.f;
#pragma unroll
    for (int e = 0; e < 4; ++e) { v[e] = Ys[r * HDIM + lane + 64 * e]; s1 += v[e]; s2 += v[e] * v[e]; }
#pragma unroll
    for (int off = 32; off > 0; off >>= 1) { s1 += __shfl_xor(s1, off, 64); s2 += __shfl_xor(s2, off, 64); }
    float m = s1 / 256.f;
    float iv = rsqrtf(s2 / 256.f - m * m + 1e-5f);
#pragma unroll
    for (int e = 0; e < 4; ++e) {
      int hd = lane + 64 * e;
      out_xp[(base + r) * HDIM + hd] = tanhf((v[e] - m) * iv * lns[hd] + lnb[hd]);
    }
  }
}

// ws float layout: [0..4095] int flags (cluster rg: ints [rg*32, rg*32+32) — 2 lines);
// per cluster rg (8 clusters), base = 4096 + rg*69632:
//   QPRE +0 (2048), KPRE +2048 (16384), MB0 +18432, MB1 +34816,
//   Z1c +51200 (8192), Z2c +59392 (8192)

// ---------------- main recurrent kernel: 8 clusters x 32 blocks ----------------
extern "C" __global__ __launch_bounds__(NTHR, 1) void omr_main(
    const float* __restrict__ Xp,
    const float* __restrict__ Wq, const float* __restrict__ bq,
    const float* __restrict__ lnqs, const float* __restrict__ lnqb,
    const float* __restrict__ Wk, const float* __restrict__ bk,
    const float* __restrict__ lnks, const float* __restrict__ lnkb,
    const float* __restrict__ Wbeta, const float* __restrict__ bbeta,
    const float* __restrict__ W1, const float* __restrict__ b1,
    const float* __restrict__ W2, const float* __restrict__ b2,
    const float* __restrict__ lns, const float* __restrict__ lnb,
    float* __restrict__ mem_out, float* __restrict__ probs_out, float* __restrict__ ws)
{
  const int tid = threadIdx.x;
  const int cg = blockIdx.x & 31;   // column group within cluster
  const int rg = blockIdx.x >> 5;   // cluster (8 clusters x 8 batch rows)
  const int ZC0 = cg * 32;          // z1/z2 cols owned
  const int QC0 = cg * 8;           // q/k/h cols owned
  const int w = tid >> 6, lane = tid & 63;
  const int rp = (lane >> 4) << 1;       // GEMM: rows rp, rp+1
  const int c2 = (lane & 15) << 1;       // GEMM: local cols c2, c2+1

  __shared__ ushort W1b[32 * 512];    // 32 KB bf16
  __shared__ ushort W2b[32 * 1024];   // 64 KB bf16
  __shared__ float Ahm[8 * 512];      // 16 KB: h | Mn(ci)
  __shared__ float Az[8 * 1024];      // 32 KB: z1 staging / qln / Wq,Wk staging
  __shared__ float redS[2048];        // 8 KB (aliases betaS/rcpS in P1)
  __shared__ float LNS_[256], LNB_[256], LNKS_[256], LNKB_[256], Wbs[256];
  __shared__ float cpS[64];
  __shared__ float b1s[32], b2s[32], bqS[8], bkS[8], bbetaS[1];

  float* cl    = ws + 4096 + (size_t)rg * 69632;
  float* QPRE  = cl;
  float* KPRE  = cl + 2048;
  float* MB0   = cl + 18432;
  float* MB1   = cl + 34816;
  float* Z1c   = cl + 51200;
  float* Z2c   = cl + 59392;
  int*   flags = (int*)ws + rg * 32;   // 32 consecutive ints = 2 cache lines
  float* betaS = redS;        // [64], P1 only
  float* rcpS  = redS + 64;   // [64], P1 only

  // ---- resident weights / params ----
  for (int e = tid; e < 32 * 512; e += NTHR) {
    int k = e >> 5, c = e & 31;
    __hip_bfloat16 h = __float2bfloat16(W1[(size_t)k * H4 + ZC0 + c]);
    W1b[W1I(c, k)] = *reinterpret_cast<ushort*>(&h);
  }
  for (int e = tid; e < 32 * 1024; e += NTHR) {
    int k = e >> 5, c = e & 31;
    __hip_bfloat16 h = __float2bfloat16(W2[(size_t)k * H4 + ZC0 + c]);
    W2b[W2I(c, k)] = *reinterpret_cast<ushort*>(&h);
  }
  if (tid < 256) {
    LNS_[tid] = lns[tid]; LNB_[tid] = lnb[tid];
    LNKS_[tid] = lnks[tid]; LNKB_[tid] = lnkb[tid];
    Wbs[tid] = Wbeta[tid];
  }
  if (tid < 32) { b1s[tid] = b1[ZC0 + tid]; b2s[tid] = b2[ZC0 + tid]; }
  if (tid < 8)  { bqS[tid] = bq[QC0 + tid]; bkS[tid] = bk[QC0 + tid]; }
  if (tid == 0) bbetaS[0] = bbeta[0];

  // ---- GEMM lambdas ----
  auto runZ1 = [&]() {
    float acc00 = 0, acc01 = 0, acc10 = 0, acc11 = 0;
    const int kb = w * 64;
#pragma unroll
    for (int kk = 0; kk < 64; kk += 8) {
      const int k = kb + kk;
      float4 a00 = *(const float4*)&Ahm[AHM(rp, k)];
      float4 a01 = *(const float4*)&Ahm[AHM(rp, k + 4)];
      float4 a10 = *(const float4*)&Ahm[AHM(rp + 1, k)];
      float4 a11 = *(const float4*)&Ahm[AHM(rp + 1, k + 4)];
      uint4 wv0 = *(const uint4*)&W1b[W1I(c2, k)];
      uint4 wv1 = *(const uint4*)&W1b[W1I(c2 + 1, k)];
      float2 p0 = bf2(wv0.x), p1 = bf2(wv0.y), p2 = bf2(wv0.z), p3 = bf2(wv0.w);
      float2 q0 = bf2(wv1.x), q1 = bf2(wv1.y), q2 = bf2(wv1.z), q3 = bf2(wv1.w);
      acc00 += a00.x*p0.x + a00.y*p0.y + a00.z*p1.x + a00.w*p1.y + a01.x*p2.x + a01.y*p2.y + a01.z*p3.x + a01.w*p3.y;
      acc01 += a00.x*q0.x + a00.y*q0.y + a00.z*q1.x + a00.w*q1.y + a01.x*q2.x + a01.y*q2.y + a01.z*q3.x + a01.w*q3.y;
      acc10 += a10.x*p0.x + a10.y*p0.y + a10.z*p1.x + a10.w*p1.y + a11.x*p2.x + a11.y*p2.y + a11.z*p3.x + a11.w*p3.y;
      acc11 += a10.x*q0.x + a10.y*q0.y + a10.z*q1.x + a10.w*q1.y + a11.x*q2.x + a11.y*q2.y + a11.z*q3.x + a11.w*q3.y;
    }
    *(float2*)&redS[REDI(w, rp, c2)]     = make_float2(acc00, acc01);
    *(float2*)&redS[REDI(w, rp + 1, c2)] = make_float2(acc10, acc11);
    __syncthreads();
    if (tid < 128) {
      int rr = tid >> 4, cc2 = (tid & 15) << 1;
      float v0 = 0, v1 = 0;
#pragma unroll
      for (int w2 = 0; w2 < 8; ++w2) {
        float2 t = *(const float2*)&redS[REDI(w2, rr, cc2)];
        v0 += t.x; v1 += t.y;
      }
      gstore2(Z1c + rr * H4 + ZC0 + cc2, fmaxf(v0 + b1s[cc2], 0.f), fmaxf(v1 + b1s[cc2 + 1], 0.f));
    }
  };

  auto runZ2 = [&]() {
    float acc00 = 0, acc01 = 0, acc10 = 0, acc11 = 0;
    const int kb = w * 128;
#pragma unroll
    for (int kk = 0; kk < 128; kk += 8) {
      const int k = kb + kk;
      float4 a00 = *(const float4*)&Az[AZi(rp, k)];
      float4 a01 = *(const float4*)&Az[AZi(rp, k + 4)];
      float4 a10 = *(const float4*)&Az[AZi(rp + 1, k)];
      float4 a11 = *(const float4*)&Az[AZi(rp + 1, k + 4)];
      uint4 wv0 = *(const uint4*)&W2b[W2I(c2, k)];
      uint4 wv1 = *(const uint4*)&W2b[W2I(c2 + 1, k)];
      float2 p0 = bf2(wv0.x), p1 = bf2(wv0.y), p2 = bf2(wv0.z), p3 = bf2(wv0.w);
      float2 q0 = bf2(wv1.x), q1 = bf2(wv1.y), q2 = bf2(wv1.z), q3 = bf2(wv1.w);
      acc00 += a00.x*p0.x + a00.y*p0.y + a00.z*p1.x + a00.w*p1.y + a01.x*p2.x + a01.y*p2.y + a01.z*p3.x + a01.w*p3.y;
      acc01 += a00.x*q0.x + a00.y*q0.y + a00.z*q1.x + a00.w*q1.y + a01.x*q2.x + a01.y*q2.y + a01.z*q3.x + a01.w*q3.y;
      acc10 += a10.x*p0.x + a10.y*p0.y + a10.z*p1.x + a10.w*p1.y + a11.x*p2.x + a11.y*p2.y + a11.z*p3.x + a11.w*p3.y;
      acc11 += a10.x*q0.x + a10.y*q0.y + a10.z*q1.x + a10.w*q1.y + a11.x*q2.x + a11.y*q2.y + a11.z*q3.x + a11.w*q3.y;
    }
    *(float2*)&redS[REDI(w, rp, c2)]     = make_float2(acc00, acc01);
    *(float2*)&redS[REDI(w, rp + 1, c2)] = make_float2(acc10, acc11);
    __syncthreads();
    if (tid < 128) {
      int rr = tid >> 4, cc2 = (tid & 15) << 1;
      float v0 = 0, v1 = 0;
#pragma unroll
      for (int w2 = 0; w2 < 8; ++w2) {
        float2 t = *(const float2*)&redS[REDI(w2, rr, cc2)];
        v0 += t.x; v1 += t.y;
      }
      gstore2(Z2c + rr * H4 + ZC0 + cc2, v0 + b2s[cc2], v1 + b2s[cc2 + 1]);
    }
  };

  // ---- t=0 init ----
  {
    int e = cg * 512 + tid;            // 16384 per cluster
    gstore(MB0 + e, 0.f);
    int r = e >> 11, hd = e & 255;
    int b = rg * ROWS + r;
    gstore(mem_out + ((size_t)b * NS + ((e >> 8) & 7)) * HDIM + hd, Xp[(size_t)b * HDIM + hd]);
    if (cg == 0 && tid < 64) gstore(probs_out + rg * 64 + tid, 0.f);
  }
  // stage Wq/Wk own cols (padded 264 layout in Az)
  for (int e = tid; e < 4096; e += NTHR) {
    int s = e >> 11, c = (e >> 8) & 7, k = e & 255;
    Az[s * 2112 + c * 264 + k] = (s ? Wk : Wq)[k * HDIM + QC0 + c];
  }
  __syncthreads();
  // S1a for t=1: qpre = Xp[1]@Wq; kpre: cM(0) identical across slots = Xp[0]
  if (tid < 64) {
    int r = tid >> 3, c = tid & 7;
    const float* Aq = Xp + (size_t)(BATCH + rg * ROWS + r) * HDIM;
    const float* Ak = Xp + (size_t)(rg * ROWS + r) * HDIM;
    const float* Wqc = Az + c * 264;
    const float* Wkc = Az + 2112 + c * 264;
    float dq = 0, dk = 0;
    for (int k = 0; k < 256; k += 4) {
      float4 aq = *(const float4*)(Aq + k);
      float4 ak = *(const float4*)(Ak + k);
      dq += aq.x * Wqc[k] + aq.y * Wqc[k + 1] + aq.z * Wqc[k + 2] + aq.w * Wqc[k + 3];
      dk += ak.x * Wkc[k] + ak.y * Wkc[k + 1] + ak.z * Wkc[k + 2] + ak.w * Wkc[k + 3];
    }
    gstore(QPRE + r * HDIM + QC0 + c, dq + bqS[c]);
    float vk = dk + bkS[c];
    for (int s = 0; s < NS; ++s) gstore(KPRE + (r * NS + s) * HDIM + QC0 + c, vk);
  }
  int ph = 0;
  cbar(flags, cg, ++ph);

  // ================= time loop =================
  for (int t = 1; t < T_LEN; ++t) {
    const size_t tb = (size_t)t * BATCH;
    const float* memPrev = mem_out + (size_t)(t - 1) * BATCH * NS * HDIM;
    float* memCur = mem_out + tb * NS * HDIM;
    const float* probsPrev = probs_out + (size_t)(t - 1) * BATCH * NS;
    float* probsCur = probs_out + tb * NS;
    float* MbOld = ((t - 1) & 1) ? MB1 : MB0;
    float* MbNew = (t & 1) ? MB1 : MB0;

    // ---------- P1 ----------
    {
      // (1) q layernorm -> qln in Az[r*256+...]
      int hd = lane * 4;
      float2 qa = gload2(QPRE + w * HDIM + hd);
      float2 qb = gload2(QPRE + w * HDIM + hd + 2);
      float s1 = qa.x + qa.y + qb.x + qb.y;
      float s2 = qa.x * qa.x + qa.y * qa.y + qb.x * qb.x + qb.y * qb.y;
#pragma unroll
      for (int m = 1; m < 64; m <<= 1) { s1 += __shfl_xor(s1, m, 64); s2 += __shfl_xor(s2, m, 64); }
      float mean = s1 * (1.f / 256.f);
      float inv = rsqrtf(s2 * (1.f / 256.f) - mean * mean + 1e-5f);
      float4 qs = *(const float4*)(lnqs + hd);
      float4 qbv = *(const float4*)(lnqb + hd);
      float4 qlv;
      qlv.x = (qa.x - mean) * inv * qs.x + qbv.x;
      qlv.y = (qa.y - mean) * inv * qs.y + qbv.y;
      qlv.z = (qb.x - mean) * inv * qs.z + qbv.z;
      qlv.w = (qb.y - mean) * inv * qs.w + qbv.w;
      *(float4*)&Az[w * 256 + hd] = qlv;
    }
    __syncthreads();
    {
      // (2) k layernorm + beta (redundant), strided element map: u8*2 + j*16
      int kr = tid >> 3, u8 = tid & 7, rr = kr >> 3;
      const float* kp = KPRE + kr * HDIM;
      float kv[32]; float s1 = 0.f, s2 = 0.f;
#pragma unroll
      for (int j = 0; j < 16; ++j) {
        float2 v = gload2(kp + u8 * 2 + j * 16);
        kv[2 * j] = v.x; kv[2 * j + 1] = v.y;
        s1 += v.x + v.y; s2 += v.x * v.x + v.y * v.y;
      }
      s1 += __shfl_xor(s1, 1, 64); s1 += __shfl_xor(s1, 2, 64); s1 += __shfl_xor(s1, 4, 64);
      s2 += __shfl_xor(s2, 1, 64); s2 += __shfl_xor(s2, 2, 64); s2 += __shfl_xor(s2, 4, 64);
      float mean = s1 * (1.f / 256.f);
      float inv = rsqrtf(s2 * (1.f / 256.f) - mean * mean + 1e-5f);
      float dot = 0.f;
#pragma unroll
      for (int j = 0; j < 16; ++j) {
        int e0 = u8 * 2 + j * 16;
        float kl0 = (kv[2 * j] - mean) * inv * LNKS_[e0] + LNKB_[e0];
        float kl1 = (kv[2 * j + 1] - mean) * inv * LNKS_[e0 + 1] + LNKB_[e0 + 1];
        dot += fmaxf(Az[rr * 256 + e0] + kl0, 0.f) * Wbs[e0];
        dot += fmaxf(Az[rr * 256 + e0 + 1] + kl1, 0.f) * Wbs[e0 + 1];
      }
      dot += __shfl_xor(dot, 1, 64); dot += __shfl_xor(dot, 2, 64); dot += __shfl_xor(dot, 4, 64);
      if (u8 == 0) betaS[kr] = (dot + bbetaS[0]) * 0.0625f;
    }
    __syncthreads();
    // (3) softmax + mask + p/cp/rcp (redundant; 8 threads)
    if (tid < 8) {
      int r = tid, b = rg * ROWS + r;
      float pp[8], pcp[8], run = 0.f;
#pragma unroll
      for (int s = 0; s < 8; s += 2) {
        float2 v = gload2(probsPrev + b * NS + s);
        pp[s] = v.x; pp[s + 1] = v.y;
      }
#pragma unroll
      for (int s = 0; s < 8; ++s) { run += pp[s]; pcp[s] = run; }
      float bmax = betaS[r * 8];
#pragma unroll
      for (int s = 1; s < 8; ++s) bmax = fmaxf(bmax, betaS[r * 8 + s]);
      float xm[8], ssum = 0.f;
#pragma unroll
      for (int s = 0; s < 8; ++s) {
        float mi;
        if (s < 7) { float cv = pcp[s + 1]; mi = (cv < 1e-5f) ? 0.f : cv; }
        else mi = 1.f;
        xm[s] = expf(betaS[r * 8 + s] - bmax) * mi;
        ssum += fabsf(xm[s]);
      }
      float denom = fmaxf(ssum, 1e-12f);
      float run2 = 0.f, pn[8];
#pragma unroll
      for (int s = 0; s < 8; ++s) {
        pn[s] = xm[s] / denom; run2 += pn[s];
        cpS[r * 8 + s] = run2;
        if (cg == r) gstore(probsCur + b * NS + s, pn[s]);
      }
      float run3 = 0.f;
#pragma unroll
      for (int s = 7; s >= 0; --s) { run3 += pn[s]; rcpS[r * 8 + s] = run3; }
    }
    __syncthreads();
    {
      // (4) M-state owner update (own 8 cols)
      int r = tid >> 6, s = (tid >> 3) & 7, c = tid & 7;
      int hd = QC0 + c;
      int idx = (r * NS + s) * HDIM + hd;
      float rc = rcpS[r * 8 + s];
      float mo = gload(MbOld + idx);
      float cm = gload(memPrev + ((size_t)(rg * ROWS + r) * NS + s) * HDIM + hd);
      gstore(MbNew + idx, mo * (1.f - rc) + cm * rc);
    }
    {
      // (5) stage Mn(slot 0) and h = Xp[t] into Ahm (redundant full rows)
      int r = tid >> 6, k4 = tid & 63, hd = k4 * 4;
      float rc0 = rcpS[r * 8];
      float2 m0 = gload2(MbOld + (r * NS) * HDIM + hd);
      float2 m1 = gload2(MbOld + (r * NS) * HDIM + hd + 2);
      float2 c0 = gload2(memPrev + ((size_t)(rg * ROWS + r) * NS) * HDIM + hd);
      float2 c1 = gload2(memPrev + ((size_t)(rg * ROWS + r) * NS) * HDIM + hd + 2);
      float4 mn = make_float4(m0.x * (1.f - rc0) + c0.x * rc0, m0.y * (1.f - rc0) + c0.y * rc0,
                              m1.x * (1.f - rc0) + c1.x * rc0, m1.y * (1.f - rc0) + c1.y * rc0);
      *(float4*)&Ahm[AHM(r, 256 + hd)] = mn;
      float4 xp4 = *(const float4*)(Xp + (tb + rg * ROWS + r) * HDIM + hd);
      *(float4*)&Ahm[AHM(r, hd)] = xp4;
    }
    __syncthreads();
    runZ1();
    cbar(flags, cg, ++ph);

    // ---------- cells ----------
    for (int ci = 0; ci < NS; ++ci) {
      // ---- Phase Z2(ci): stage z1 -> Az (single round), GEMM ----
      {
        int r = tid >> 6, ks = (tid & 63) * 16;
        const float* zp = Z1c + r * H4 + ks;
#pragma unroll
        for (int q = 0; q < 4; ++q) {
          float2 v0 = gload2(zp + q * 4);
          float2 v1 = gload2(zp + q * 4 + 2);
          *(float4*)&Az[AZi(r, ks + q * 4)] = make_float4(v0.x, v0.y, v1.x, v1.y);
        }
      }
      __syncthreads();
      runZ2();
      cbar(flags, cg, ++ph);

      // ---- Phase H(ci) + Z1(ci+1) / S1a ----
      {
        const int rw = w;
        const int hd = lane * 4;
        const float* z2r = Z2c + rw * H4;
        // prefetch Mn(ci+1) from MbNew
        float4 mnN = make_float4(0.f, 0.f, 0.f, 0.f);
        if (ci < 7) {
          float2 a = gload2(MbNew + (rw * NS + ci + 1) * HDIM + hd);
          float2 b = gload2(MbNew + (rw * NS + ci + 1) * HDIM + hd + 2);
          mnN = make_float4(a.x, a.y, b.x, b.y);
        }
        float2 cA = gload2(z2r + 768 + hd);
        float2 cB = gload2(z2r + 768 + hd + 2);
        float g[12];
#pragma unroll
        for (int j = 0; j < 6; ++j) {
          float2 v = gload2(z2r + hd * 3 + 2 * j);
          g[2 * j] = v.x; g[2 * j + 1] = v.y;
        }
        float4 hi4 = *(const float4*)&Ahm[AHM(rw, 256 + hd)];
        float4 vi4 = *(const float4*)&Ahm[AHM(rw, hd)];
        float4 xp4 = *(const float4*)(Xp + (tb + rg * ROWS + rw) * HDIM + hd);
        float s1 = cA.x + cA.y + cB.x + cB.y;
        float s2 = cA.x * cA.x + cA.y * cA.y + cB.x * cB.x + cB.y * cB.y;
#pragma unroll
        for (int m = 1; m < 64; m <<= 1) { s1 += __shfl_xor(s1, m, 64); s2 += __shfl_xor(s2, m, 64); }
        float mean = s1 * (1.f / 256.f);
        float inv = rsqrtf(s2 * (1.f / 256.f) - mean * mean + 1e-5f);
        float cp = cpS[rw * 8 + ci];
        float ccv[4] = {cA.x, cA.y, cB.x, cB.y};
        float hiv[4] = {hi4.x, hi4.y, hi4.z, hi4.w};
        float viv[4] = {vi4.x, vi4.y, vi4.z, vi4.w};
        float xpv[4] = {xp4.x, xp4.y, xp4.z, xp4.w};
        float hn[4];
#pragma unroll
        for (int j = 0; j < 4; ++j) {
          float z0 = g[3 * j], z1v = g[3 * j + 1], z2g = g[3 * j + 2];
          float gm = fmaxf(z0, fmaxf(z1v, z2g));
          float e0 = expf(z0 - gm), e1 = expf(z1v - gm), e2 = expf(z2g - gm);
          float act = tanhf((ccv[j] - mean) * inv * LNS_[hd + j] + LNB_[hd + j]);
          float hc = (e0 * viv[j] + e1 * hiv[j] + e2 * act) / (e0 + e1 + e2);
          hn[j] = xpv[j] * (1.f - cp) + hc * cp;
        }
        if ((lane >> 1) == cg) {
          float* mp = memCur + ((size_t)(rg * ROWS + rw) * NS + ci) * HDIM + hd;
          gstore2(mp, hn[0], hn[1]);
          gstore2(mp + 2, hn[2], hn[3]);
        }
        *(float4*)&Ahm[AHM(rw, hd)] = make_float4(hn[0], hn[1], hn[2], hn[3]);
        if (ci < 7) *(float4*)&Ahm[AHM(rw, 256 + hd)] = mnN;
      }
      __syncthreads();

      if (ci < 7) {
        runZ1();
      } else if (t < T_LEN - 1) {
        // ---- S1a(t+1) ----
        for (int e = tid; e < 4096; e += NTHR) {
          int s = e >> 11, c = (e >> 8) & 7, k = e & 255;
          Az[s * 2112 + c * 264 + k] = (s ? Wk : Wq)[k * HDIM + QC0 + c];
        }
        __syncthreads();
        {
          int kr = tid >> 3, c = tid & 7;
          int rr = kr >> 3, s = kr & 7;
          const float* Wc = Az + 2112 + c * 264;
          float d = 0.f;
          if (s < 7) {
            const float* A = memCur + ((size_t)(rg * ROWS + rr) * NS + s) * HDIM;
            for (int k = 0; k < 256; k += 2) {
              float2 a = gload2(A + k);
              d += a.x * Wc[k] + a.y * Wc[k + 1];
            }
          } else {
            for (int k = 0; k < 256; k += 4) {
              float4 a = *(const float4*)&Ahm[AHM(rr, k)];
              d += a.x * Wc[k] + a.y * Wc[k + 1] + a.z * Wc[k + 2] + a.w * Wc[k + 3];
            }
          }
          gstore(KPRE + kr * HDIM + QC0 + c, d + bkS[c]);
          if (tid < 64) {
            int qr = tid >> 3, qc = tid & 7;
            const float* A = Xp + ((size_t)(t + 1) * BATCH + rg * ROWS + qr) * HDIM;
            const float* Wqc = Az + qc * 264;
            float dq = 0.f;
            for (int k = 0; k < 256; k += 4) {
              float4 a = *(const float4*)(A + k);
              dq += a.x * Wqc[k] + a.y * Wqc[k + 1] + a.z * Wqc[k + 2] + a.w * Wqc[k + 3];
            }
            gstore(QPRE + qr * HDIM + QC0 + qc, dq + bqS[qc]);
          }
        }
      }
      cbar(flags, cg, ++ph);
    }
  }
}

extern "C" void kernel_launch(void* const* d_in, const int* in_sizes, int n_in,
                              void* d_out, int out_size, void* d_ws, size_t ws_size,
                              hipStream_t stream) {
  (void)in_sizes; (void)n_in; (void)out_size; (void)ws_size;
  const float* X     = (const float*)d_in[0];
  const float* Wp    = (const float*)d_in[3];
  const float* bp    = (const float*)d_in[4];
  const float* lns   = (const float*)d_in[5];
  const float* lnb   = (const float*)d_in[6];
  const float* Wq    = (const float*)d_in[7];
  const float* bq    = (const float*)d_in[8];
  const float* lnqs  = (const float*)d_in[9];
  const float* lnqb  = (const float*)d_in[10];
  const float* Wk    = (const float*)d_in[11];
  const float* bk    = (const float*)d_in[12];
  const float* lnks  = (const float*)d_in[13];
  const float* lnkb  = (const float*)d_in[14];
  const float* Wbeta = (const float*)d_in[15];
  const float* bbeta = (const float*)d_in[16];
  const float* W1    = (const float*)d_in[17];
  const float* b1    = (const float*)d_in[18];
  const float* W2    = (const float*)d_in[19];
  const float* b2    = (const float*)d_in[20];

  float* out       = (float*)d_out;
  float* out_xp    = out;
  float* out_mem   = out + (size_t)T_LEN * BATCH * HDIM;
  float* out_probs = out_mem + (size_t)T_LEN * BATCH * NS * HDIM;
  float* ws        = (float*)d_ws;

  hipLaunchKernelGGL(init_ctrl, dim3(16), dim3(256), 0, stream, (int*)d_ws);
  hipLaunchKernelGGL(xp_kernel, dim3(1024), dim3(256), 0, stream, X, Wp, bp, lns, lnb, out_xp);
  hipLaunchKernelGGL(omr_main, dim3(256), dim3(NTHR), 0, stream,
                     out_xp, Wq, bq, lnqs, lnqb, Wk, bk, lnks, lnkb, Wbeta, bbeta,
                     W1, b1, W2, b2, lns, lnb, out_mem, out_probs, ws);
}

// Round 6
// 29767.340 us; speedup vs baseline: 1.6964x; 1.6964x over previous
//
#include <hip/hip_runtime.h>
#include <hip/hip_bf16.h>
#include <math.h>

#define T_LEN 128
#define BATCH 64
#define IND   512
#define HDIM  256
#define NS    8
#define H4    1024
#define NTHR  512

typedef unsigned long long ull;
typedef unsigned int uint;
typedef unsigned short ushort;

// ---- LLC-coherent accessors (bypass per-XCD L2): agent-scope relaxed atomics ----
__device__ __forceinline__ float gload(const float* p) {
  return __hip_atomic_load(p, __ATOMIC_RELAXED, __HIP_MEMORY_SCOPE_AGENT);
}
__device__ __forceinline__ float2 gload2(const float* p) {
  ull v = __hip_atomic_load((const ull*)p, __ATOMIC_RELAXED, __HIP_MEMORY_SCOPE_AGENT);
  return __builtin_bit_cast(float2, v);
}
__device__ __forceinline__ void gstore(float* p, float v) {
  __hip_atomic_store(p, v, __ATOMIC_RELAXED, __HIP_MEMORY_SCOPE_AGENT);
}
__device__ __forceinline__ void gstore2(float* p, float a, float b) {
  float2 t = make_float2(a, b);
  __hip_atomic_store((ull*)p, __builtin_bit_cast(ull, t), __ATOMIC_RELAXED, __HIP_MEMORY_SCOPE_AGENT);
}

__device__ __forceinline__ float2 bf2(uint u) {
  return make_float2(__uint_as_float(u << 16), __uint_as_float(u & 0xffff0000u));
}
// 8 bf16 weights vs 8 fp32 A values -> acc
__device__ __forceinline__ void fma8(float& acc, float4 x0, float4 x1, uint4 u) {
  float2 wA = bf2(u.x), wB = bf2(u.y), wC = bf2(u.z), wD = bf2(u.w);
  acc += x0.x * wA.x + x0.y * wA.y + x0.z * wB.x + x0.w * wB.y
       + x1.x * wC.x + x1.y * wC.y + x1.z * wD.x + x1.w * wD.y;
}

// ---- per-cluster barrier: 64 blocks, packed flags (4 lines), per-lane exit ----
__device__ __forceinline__ void cbar(int* flags, int cg, int ph) {
  asm volatile("s_waitcnt vmcnt(0)" ::: "memory");
  __syncthreads();
  if (threadIdx.x == 0)
    __hip_atomic_store(flags + cg, ph, __ATOMIC_RELAXED, __HIP_MEMORY_SCOPE_AGENT);
  if (threadIdx.x < 64) {
    while (__hip_atomic_load(flags + threadIdx.x, __ATOMIC_RELAXED, __HIP_MEMORY_SCOPE_AGENT) < ph)
      __builtin_amdgcn_s_sleep(1);
  }
  __syncthreads();
}

extern "C" __global__ void init_ctrl(int* ctrl) {
  int t = blockIdx.x * blockDim.x + threadIdx.x;
  if (t < 1024) ctrl[t] = 0;
}

// ---------------- Xp = tanh(LN(X @ W_proj + b)) ----------------
extern "C" __global__ __launch_bounds__(256) void xp_kernel(
    const float* __restrict__ X, const float* __restrict__ Wp, const float* __restrict__ bp,
    const float* __restrict__ lns, const float* __restrict__ lnb, float* __restrict__ out_xp)
{
  __shared__ float Xs[8 * IND];
  __shared__ float Ys[8 * HDIM];
  const int tid = threadIdx.x;
  const size_t base = (size_t)blockIdx.x * 8;
  const float* Xb = X + base * IND;
  for (int e = tid; e < 8 * IND / 4; e += 256) ((float4*)Xs)[e] = ((const float4*)Xb)[e];
  __syncthreads();
  float acc[8];
#pragma unroll
  for (int r = 0; r < 8; ++r) acc[r] = 0.f;
  for (int k = 0; k < IND; ++k) {
    float wv = Wp[k * HDIM + tid];
#pragma unroll
    for (int r = 0; r < 8; ++r) acc[r] += Xs[r * IND + k] * wv;
  }
  float bpv = bp[tid];
#pragma unroll
  for (int r = 0; r < 8; ++r) Ys[r * HDIM + tid] = acc[r] + bpv;
  __syncthreads();
  int w = tid >> 6, lane = tid & 63;
  for (int rr = 0; rr < 2; ++rr) {
    int r = w * 2 + rr;
    float v[4]; float s1 = 0.f, s2 = 0.f;
#pragma unroll
    for (int e = 0; e < 4; ++e) { v[e] = Ys[r * HDIM + lane + 64 * e]; s1 += v[e]; s2 += v[e] * v[e]; }
#pragma unroll
    for (int off = 32; off > 0; off >>= 1) { s1 += __shfl_xor(s1, off, 64); s2 += __shfl_xor(s2, off, 64); }
    float m = s1 / 256.f;
    float iv = rsqrtf(s2 / 256.f - m * m + 1e-5f);
#pragma unroll
    for (int e = 0; e < 4; ++e) {
      int hd = lane + 64 * e;
      out_xp[(base + r) * HDIM + hd] = tanhf((v[e] - m) * iv * lns[hd] + lnb[hd]);
    }
  }
}

// ws float layout: [0..1023] int flags (cluster rg: ints [rg*64, rg*64+64));
// data base = 1024; per cluster rg (4 clusters), size 135168:
//   QPRE +0 (4096), KPRE +4096 (32768), MB0 +36864, MB1 +69632,
//   Z1c +102400 (16384), Z2c +118784 (16384)

// ---------------- main recurrent kernel: 4 clusters x 64 blocks ----------------
extern "C" __global__ __launch_bounds__(NTHR, 1) void omr_main(
    const float* __restrict__ Xp,
    const float* __restrict__ Wq, const float* __restrict__ bq,
    const float* __restrict__ lnqs, const float* __restrict__ lnqb,
    const float* __restrict__ Wk, const float* __restrict__ bk,
    const float* __restrict__ lnks, const float* __restrict__ lnkb,
    const float* __restrict__ Wbeta, const float* __restrict__ bbeta,
    const float* __restrict__ W1, const float* __restrict__ b1,
    const float* __restrict__ W2, const float* __restrict__ b2,
    const float* __restrict__ lns, const float* __restrict__ lnb,
    float* __restrict__ mem_out, float* __restrict__ probs_out, float* __restrict__ ws)
{
  const int tid = threadIdx.x;
  const int cg = blockIdx.x & 63;   // column group
  const int rg = blockIdx.x >> 6;   // cluster (4 clusters x 16 batch rows)
  const int ZC0 = cg * 16;          // z1/z2 cols owned
  const int QC0 = cg * 4;           // q/k/h cols owned
  const int w = tid >> 6, lane = tid & 63;
  const int rl = lane >> 3, cl = lane & 7;   // 8x8 lane grid; outputs (rl,rl+8)x(cl,cl+8)

  // LDS ~131 KB, all hot GEMM strides ≡ 4 mod 32 banks (conflict-free 8-quad spread)
  __shared__ ushort W1b[16 * 520];    // bf16 W1 col slice
  __shared__ ushort W2b[16 * 1032];   // bf16 W2 col slice
  __shared__ float hlocS[16 * 260];   // current h rows
  __shared__ float AstS[16 * 260];    // Mn(ci) staging
  __shared__ float Azc[16 * 516];     // z1 chunk staging / P1 qln / S1a Wq-Wk
  __shared__ float redS[8 * 260];     // split-K partials
  __shared__ float LNS_[256], LNB_[256], LNKS_[256], LNKB_[256], Wbs[256];
  __shared__ float cpS[128], rcpS[128], betaS[128];
  __shared__ float b1s[16], b2s[16], bqS[4], bkS[4], bbetaS[1];

  float* cl_   = ws + 1024 + (size_t)rg * 135168;
  float* QPRE  = cl_;
  float* KPRE  = cl_ + 4096;
  float* MB0   = cl_ + 36864;
  float* MB1   = cl_ + 69632;
  float* Z1c   = cl_ + 102400;
  float* Z2c   = cl_ + 118784;
  int*   flags = (int*)ws + rg * 64;

  // ---- resident weights / params ----
  for (int e = tid; e < 16 * 512; e += NTHR) {
    int k = e >> 4, c = e & 15;
    __hip_bfloat16 h = __float2bfloat16(W1[(size_t)k * H4 + ZC0 + c]);
    W1b[c * 520 + k] = *reinterpret_cast<ushort*>(&h);
  }
  for (int e = tid; e < 16 * 1024; e += NTHR) {
    int k = e >> 4, c = e & 15;
    __hip_bfloat16 h = __float2bfloat16(W2[(size_t)k * H4 + ZC0 + c]);
    W2b[c * 1032 + k] = *reinterpret_cast<ushort*>(&h);
  }
  if (tid < 256) {
    LNS_[tid] = lns[tid];  LNB_[tid] = lnb[tid];
    LNKS_[tid] = lnks[tid]; LNKB_[tid] = lnkb[tid];
    Wbs[tid] = Wbeta[tid];
  }
  if (tid < 16) { b1s[tid] = b1[ZC0 + tid]; b2s[tid] = b2[ZC0 + tid]; }
  if (tid < 4)  { bqS[tid] = bq[QC0 + tid]; bkS[tid] = bk[QC0 + tid]; }
  if (tid == 0) bbetaS[0] = bbeta[0];

  // ---- Z1 GEMM: 16x16 tile, waves 0-3 = h K-slices, 4-7 = Mn K-slices ----
  auto runZ1 = [&]() {
    const float* Ap = (w < 4) ? hlocS : AstS;
    const int kb = (w & 3) * 64;
    const int kgb = w * 64;
    float a00 = 0, a01 = 0, a10 = 0, a11 = 0;
#pragma unroll
    for (int kk = 0; kk < 64; kk += 8) {
      const int ka = kb + kk, kw = kgb + kk;
      float4 x0 = *(const float4*)&Ap[rl * 260 + ka];
      float4 x1 = *(const float4*)&Ap[rl * 260 + ka + 4];
      float4 y0 = *(const float4*)&Ap[(rl + 8) * 260 + ka];
      float4 y1 = *(const float4*)&Ap[(rl + 8) * 260 + ka + 4];
      uint4 u0 = *(const uint4*)&W1b[cl * 520 + kw];
      uint4 u1 = *(const uint4*)&W1b[(cl + 8) * 520 + kw];
      fma8(a00, x0, x1, u0); fma8(a01, x0, x1, u1);
      fma8(a10, y0, y1, u0); fma8(a11, y0, y1, u1);
    }
    redS[w * 260 + rl * 16 + cl] = a00;
    redS[w * 260 + rl * 16 + cl + 8] = a01;
    redS[w * 260 + (rl + 8) * 16 + cl] = a10;
    redS[w * 260 + (rl + 8) * 16 + cl + 8] = a11;
    __syncthreads();
    if (tid < 256) {
      float v = 0.f;
#pragma unroll
      for (int w2 = 0; w2 < 8; ++w2) v += redS[w2 * 260 + tid];
      int r = tid >> 4, c = tid & 15;
      gstore(Z1c + r * H4 + ZC0 + c, fmaxf(v + b1s[c], 0.f));
    }
  };

  // ---- t=0 init ----
  {
    int e = cg * 512 + tid;            // 32768 per cluster
    gstore(MB0 + e, 0.f);
    int r = e >> 11, hd = e & 255;
    int b = rg * 16 + r;
    gstore(mem_out + ((size_t)b * NS + ((e >> 8) & 7)) * HDIM + hd, Xp[(size_t)b * HDIM + hd]);
    if (cg == 0 && tid < 128) gstore(probs_out + rg * 128 + tid, 0.f);
  }
  // stage Wq/Wk own cols into Azc; S1a for t=1 (cM(0) rows = Xp[0], all slots equal)
  for (int e = tid; e < 2048; e += NTHR) {
    int s = e >> 10, c = (e >> 8) & 3, k = e & 255;
    Azc[s * 1040 + c * 260 + k] = (s ? Wk : Wq)[k * HDIM + QC0 + c];
  }
  __syncthreads();
  if (tid < 32) {
    bool isq = tid < 16;
    int row = tid & 15;
    const float* A = Xp + (size_t)((isq ? BATCH : 0) + rg * 16 + row) * HDIM;
    float d[4] = {0, 0, 0, 0};
    for (int k = 0; k < 256; k += 4) {
      float4 a = *(const float4*)(A + k);
#pragma unroll
      for (int c = 0; c < 4; ++c) {
        const float* Wc = Azc + (isq ? 0 : 1040) + c * 260;
        d[c] += a.x * Wc[k] + a.y * Wc[k + 1] + a.z * Wc[k + 2] + a.w * Wc[k + 3];
      }
    }
#pragma unroll
    for (int c = 0; c < 4; ++c) {
      if (isq) gstore(QPRE + row * HDIM + QC0 + c, d[c] + bqS[c]);
      else { float vk = d[c] + bkS[c]; for (int s = 0; s < NS; ++s) gstore(KPRE + (row * NS + s) * HDIM + QC0 + c, vk); }
    }
  }
  int ph = 0;
  cbar(flags, cg, ++ph);

  // ================= time loop =================
  for (int t = 1; t < T_LEN; ++t) {
    const size_t tb = (size_t)t * BATCH;
    const float* memPrev = mem_out + (size_t)(t - 1) * BATCH * NS * HDIM;
    float* memCur = mem_out + tb * NS * HDIM;
    const float* probsPrev = probs_out + (size_t)(t - 1) * BATCH * NS;
    float* probsCur = probs_out + tb * NS;
    float* MbOld = ((t - 1) & 1) ? MB1 : MB0;
    float* MbNew = (t & 1) ? MB1 : MB0;
    const int r5 = tid >> 5, u5 = tid & 31, hd0 = u5 * 8;

    // ---------- P1 ----------
    {
      // (1) q layernorm -> Azc[r5*516 + hd]
      float q[8]; float s1 = 0.f, s2 = 0.f;
#pragma unroll
      for (int j = 0; j < 4; ++j) {
        float2 v = gload2(QPRE + r5 * HDIM + hd0 + 2 * j);
        q[2 * j] = v.x; q[2 * j + 1] = v.y;
        s1 += v.x + v.y; s2 += v.x * v.x + v.y * v.y;
      }
#pragma unroll
      for (int m = 1; m < 32; m <<= 1) { s1 += __shfl_xor(s1, m, 64); s2 += __shfl_xor(s2, m, 64); }
      float mean = s1 * (1.f / 256.f);
      float inv = rsqrtf(s2 * (1.f / 256.f) - mean * mean + 1e-5f);
#pragma unroll
      for (int j = 0; j < 8; ++j)
        Azc[r5 * 516 + hd0 + j] = (q[j] - mean) * inv * lnqs[hd0 + j] + lnqb[hd0 + j];
    }
    __syncthreads();
    {
      // (2) k layernorm + beta (redundant per block; 4 threads/k-row)
      int kr = tid >> 2, u4 = tid & 3, rr = kr >> 3;
      const float* kp = KPRE + kr * HDIM + u4 * 64;
      float kv[64]; float s1 = 0.f, s2 = 0.f;
#pragma unroll
      for (int e = 0; e < 32; ++e) {
        float2 v = gload2(kp + 2 * e);
        kv[2 * e] = v.x; kv[2 * e + 1] = v.y;
        s1 += v.x + v.y; s2 += v.x * v.x + v.y * v.y;
      }
      s1 += __shfl_xor(s1, 1, 64); s1 += __shfl_xor(s1, 2, 64);
      s2 += __shfl_xor(s2, 1, 64); s2 += __shfl_xor(s2, 2, 64);
      float mean = s1 * (1.f / 256.f);
      float inv = rsqrtf(s2 * (1.f / 256.f) - mean * mean + 1e-5f);
      float dot = 0.f;
#pragma unroll
      for (int e = 0; e < 64; ++e) {
        int hd = u4 * 64 + e;
        float kl = (kv[e] - mean) * inv * LNKS_[hd] + LNKB_[hd];
        float rv = fmaxf(Azc[rr * 516 + hd] + kl, 0.f);
        dot += rv * Wbs[hd];
      }
      dot += __shfl_xor(dot, 1, 64); dot += __shfl_xor(dot, 2, 64);
      if (u4 == 0) betaS[kr] = (dot + bbetaS[0]) * 0.0625f;
    }
    __syncthreads();
    // (3) softmax + mask + p/cp/rcp (redundant; 16 threads)
    if (tid < 16) {
      int r = tid, b = rg * 16 + r;
      float pp[8], pcp[8], run = 0.f;
#pragma unroll
      for (int s = 0; s < 8; s += 2) {
        float2 v = gload2(probsPrev + b * NS + s);
        pp[s] = v.x; pp[s + 1] = v.y;
      }
#pragma unroll
      for (int s = 0; s < 8; ++s) { run += pp[s]; pcp[s] = run; }
      float bmax = betaS[r * 8];
#pragma unroll
      for (int s = 1; s < 8; ++s) bmax = fmaxf(bmax, betaS[r * 8 + s]);
      float xm[8], ssum = 0.f;
#pragma unroll
      for (int s = 0; s < 8; ++s) {
        float mi;
        if (s < 7) { float cv = pcp[s + 1]; mi = (cv < 1e-5f) ? 0.f : cv; }
        else mi = 1.f;
        xm[s] = expf(betaS[r * 8 + s] - bmax) * mi;
        ssum += fabsf(xm[s]);
      }
      float denom = fmaxf(ssum, 1e-12f);
      float run2 = 0.f, pn[8];
#pragma unroll
      for (int s = 0; s < 8; ++s) {
        pn[s] = xm[s] / denom; run2 += pn[s];
        cpS[r * 8 + s] = run2;
        if (cg == r) gstore(probsCur + b * NS + s, pn[s]);
      }
      float run3 = 0.f;
#pragma unroll
      for (int s = 7; s >= 0; --s) { run3 += pn[s]; rcpS[r * 8 + s] = run3; }
    }
    __syncthreads();
    {
      // (4) M-state owner update (own 4 cols, all 16 rows x 8 slots)
      int r = tid >> 5, s = (tid >> 2) & 7, c = tid & 3;
      int hd = QC0 + c;
      int idx = (r * NS + s) * HDIM + hd;
      float rc = rcpS[r * 8 + s];
      float mo = gload(MbOld + idx);
      float cm = gload(memPrev + ((size_t)(rg * 16 + r) * NS + s) * HDIM + hd);
      gstore(MbNew + idx, mo * (1.f - rc) + cm * rc);
    }
    {
      // (5) stage Mn(slot0)=blend(MbOld,memPrev) and h=Xp[t] (lane-consecutive writes)
      float rc0 = rcpS[r5 * 8];
#pragma unroll
      for (int jj = 0; jj < 2; ++jj) {
        int k = u5 * 4 + jj * 128;
        float2 m0 = gload2(MbOld + (r5 * NS) * HDIM + k);
        float2 m1 = gload2(MbOld + (r5 * NS) * HDIM + k + 2);
        float2 c0 = gload2(memPrev + ((size_t)(rg * 16 + r5) * NS) * HDIM + k);
        float2 c1 = gload2(memPrev + ((size_t)(rg * 16 + r5) * NS) * HDIM + k + 2);
        *(float4*)&AstS[r5 * 260 + k] = make_float4(
            m0.x * (1.f - rc0) + c0.x * rc0, m0.y * (1.f - rc0) + c0.y * rc0,
            m1.x * (1.f - rc0) + c1.x * rc0, m1.y * (1.f - rc0) + c1.y * rc0);
        *(float4*)&hlocS[r5 * 260 + k] = *(const float4*)&Xp[(tb + rg * 16 + r5) * HDIM + k];
      }
    }
    __syncthreads();
    runZ1();
    cbar(flags, cg, ++ph);

    // ---------- cells ----------
    for (int ci = 0; ci < NS; ++ci) {
      // ---- Z2(ci): 2 chunks of K=512 staged into Azc ----
      {
        float a00 = 0, a01 = 0, a10 = 0, a11 = 0;
        for (int ch = 0; ch < 2; ++ch) {
#pragma unroll
          for (int jj = 0; jj < 4; ++jj) {
            int k = u5 * 4 + jj * 128;
            float2 v0 = gload2(Z1c + r5 * H4 + ch * 512 + k);
            float2 v1 = gload2(Z1c + r5 * H4 + ch * 512 + k + 2);
            *(float4*)&Azc[r5 * 516 + k] = make_float4(v0.x, v0.y, v1.x, v1.y);
          }
          __syncthreads();
          const int kb = w * 64;
          const int kw0 = ch * 512 + kb;
#pragma unroll
          for (int kk = 0; kk < 64; kk += 8) {
            float4 x0 = *(const float4*)&Azc[rl * 516 + kb + kk];
            float4 x1 = *(const float4*)&Azc[rl * 516 + kb + kk + 4];
            float4 y0 = *(const float4*)&Azc[(rl + 8) * 516 + kb + kk];
            float4 y1 = *(const float4*)&Azc[(rl + 8) * 516 + kb + kk + 4];
            uint4 u0 = *(const uint4*)&W2b[cl * 1032 + kw0 + kk];
            uint4 u1 = *(const uint4*)&W2b[(cl + 8) * 1032 + kw0 + kk];
            fma8(a00, x0, x1, u0); fma8(a01, x0, x1, u1);
            fma8(a10, y0, y1, u0); fma8(a11, y0, y1, u1);
          }
          __syncthreads();
        }
        redS[w * 260 + rl * 16 + cl] = a00;
        redS[w * 260 + rl * 16 + cl + 8] = a01;
        redS[w * 260 + (rl + 8) * 16 + cl] = a10;
        redS[w * 260 + (rl + 8) * 16 + cl + 8] = a11;
        __syncthreads();
        if (tid < 256) {
          float v = 0.f;
#pragma unroll
          for (int w2 = 0; w2 < 8; ++w2) v += redS[w2 * 260 + tid];
          int r = tid >> 4, c = tid & 15;
          gstore(Z2c + r * H4 + ZC0 + c, v + b2s[c]);
        }
      }
      cbar(flags, cg, ++ph);

      // ---- H(ci): redundant full-h update; hi from LDS AstS ----
      {
        const float* z2r = Z2c + r5 * H4;
        float cc[8]; float s1 = 0.f, s2 = 0.f;
#pragma unroll
        for (int j = 0; j < 4; ++j) {
          float2 v = gload2(z2r + 768 + hd0 + 2 * j);
          cc[2 * j] = v.x; cc[2 * j + 1] = v.y;
          s1 += v.x + v.y; s2 += v.x * v.x + v.y * v.y;
        }
#pragma unroll
        for (int m = 1; m < 32; m <<= 1) { s1 += __shfl_xor(s1, m, 64); s2 += __shfl_xor(s2, m, 64); }
        float mean = s1 * (1.f / 256.f);
        float inv = rsqrtf(s2 * (1.f / 256.f) - mean * mean + 1e-5f);
        float g[24];
#pragma unroll
        for (int j = 0; j < 12; ++j) {
          float2 v = gload2(z2r + hd0 * 3 + 2 * j);
          g[2 * j] = v.x; g[2 * j + 1] = v.y;
        }
        float4 hiA = *(const float4*)&AstS[r5 * 260 + hd0];
        float4 hiB = *(const float4*)&AstS[r5 * 260 + hd0 + 4];
        float4 viA = *(const float4*)&hlocS[r5 * 260 + hd0];
        float4 viB = *(const float4*)&hlocS[r5 * 260 + hd0 + 4];
        float4 xpA = *(const float4*)&Xp[(tb + rg * 16 + r5) * HDIM + hd0];
        float4 xpB = *(const float4*)&Xp[(tb + rg * 16 + r5) * HDIM + hd0 + 4];
        float hiv[8] = {hiA.x, hiA.y, hiA.z, hiA.w, hiB.x, hiB.y, hiB.z, hiB.w};
        float viv[8] = {viA.x, viA.y, viA.z, viA.w, viB.x, viB.y, viB.z, viB.w};
        float xpv[8] = {xpA.x, xpA.y, xpA.z, xpA.w, xpB.x, xpB.y, xpB.z, xpB.w};
        float cp = cpS[r5 * 8 + ci];
        float hn[8];
#pragma unroll
        for (int j = 0; j < 8; ++j) {
          int hd = hd0 + j;
          float z0 = g[3 * j], z1v = g[3 * j + 1], z2g = g[3 * j + 2];
          float gm = fmaxf(z0, fmaxf(z1v, z2g));
          float e0 = expf(z0 - gm), e1 = expf(z1v - gm), e2 = expf(z2g - gm);
          float act = tanhf((cc[j] - mean) * inv * LNS_[hd] + LNB_[hd]);
          float hc = (e0 * viv[j] + e1 * hiv[j] + e2 * act) / (e0 + e1 + e2);
          hn[j] = xpv[j] * (1.f - cp) + hc * cp;
        }
        *(float4*)&hlocS[r5 * 260 + hd0] = make_float4(hn[0], hn[1], hn[2], hn[3]);
        *(float4*)&hlocS[r5 * 260 + hd0 + 4] = make_float4(hn[4], hn[5], hn[6], hn[7]);
        if (hd0 == (QC0 & ~7)) {
          int o4 = QC0 & 4;
          float* mp = memCur + ((size_t)(rg * 16 + r5) * NS + ci) * HDIM + QC0;
          gstore2(mp, hn[o4], hn[o4 + 1]);
          gstore2(mp + 2, hn[o4 + 2], hn[o4 + 3]);
        }
      }
      __syncthreads();

      if (ci < 7) {
        // restage AstS = MbNew slot ci+1 (already fully blended in P1)
#pragma unroll
        for (int jj = 0; jj < 2; ++jj) {
          int k = u5 * 4 + jj * 128;
          float2 a = gload2(MbNew + (r5 * NS + ci + 1) * HDIM + k);
          float2 b = gload2(MbNew + (r5 * NS + ci + 1) * HDIM + k + 2);
          *(float4*)&AstS[r5 * 260 + k] = make_float4(a.x, a.y, b.x, b.y);
        }
        __syncthreads();
        runZ1();
      } else if (t < T_LEN - 1) {
        // ---- S1a(t+1): dedup — one thread per row ----
        for (int e = tid; e < 2048; e += NTHR) {
          int s = e >> 10, c = (e >> 8) & 3, k = e & 255;
          Azc[s * 1040 + c * 260 + k] = (s ? Wk : Wq)[k * HDIM + QC0 + c];
        }
        __syncthreads();
        if (tid < 144) {
          bool isq = tid < 16;
          float d0 = 0, d1 = 0, d2 = 0, d3 = 0;
          if (isq) {
            int row = tid;
            const float* A = Xp + ((size_t)(t + 1) * BATCH + rg * 16 + row) * HDIM;
            const float* W0 = Azc, *W1c = Azc + 260, *W2c = Azc + 520, *W3c = Azc + 780;
            for (int k = 0; k < 256; k += 4) {
              float4 a = *(const float4*)(A + k);
              d0 += a.x * W0[k] + a.y * W0[k + 1] + a.z * W0[k + 2] + a.w * W0[k + 3];
              d1 += a.x * W1c[k] + a.y * W1c[k + 1] + a.z * W1c[k + 2] + a.w * W1c[k + 3];
              d2 += a.x * W2c[k] + a.y * W2c[k + 1] + a.z * W2c[k + 2] + a.w * W2c[k + 3];
              d3 += a.x * W3c[k] + a.y * W3c[k + 1] + a.z * W3c[k + 2] + a.w * W3c[k + 3];
            }
            gstore(QPRE + row * HDIM + QC0 + 0, d0 + bqS[0]);
            gstore(QPRE + row * HDIM + QC0 + 1, d1 + bqS[1]);
            gstore(QPRE + row * HDIM + QC0 + 2, d2 + bqS[2]);
            gstore(QPRE + row * HDIM + QC0 + 3, d3 + bqS[3]);
          } else {
            int row = tid - 16;              // 0..127 = rr*8+s
            int rr = row >> 3, s = row & 7;
            const float* W0 = Azc + 1040, *W1c = Azc + 1300, *W2c = Azc + 1560, *W3c = Azc + 1820;
            if (s < 7) {
              const float* A = memCur + ((size_t)(rg * 16 + rr) * NS + s) * HDIM;
              for (int k = 0; k < 256; k += 2) {
                float2 a = gload2(A + k);
                d0 += a.x * W0[k] + a.y * W0[k + 1];
                d1 += a.x * W1c[k] + a.y * W1c[k + 1];
                d2 += a.x * W2c[k] + a.y * W2c[k + 1];
                d3 += a.x * W3c[k] + a.y * W3c[k + 1];
              }
            } else {
              const float* A = &hlocS[rr * 260];
              for (int k = 0; k < 256; k += 4) {
                float4 a = *(const float4*)(A + k);
                d0 += a.x * W0[k] + a.y * W0[k + 1] + a.z * W0[k + 2] + a.w * W0[k + 3];
                d1 += a.x * W1c[k] + a.y * W1c[k + 1] + a.z * W1c[k + 2] + a.w * W1c[k + 3];
                d2 += a.x * W2c[k] + a.y * W2c[k + 1] + a.z * W2c[k + 2] + a.w * W2c[k + 3];
                d3 += a.x * W3c[k] + a.y * W3c[k + 1] + a.z * W3c[k + 2] + a.w * W3c[k + 3];
              }
            }
            gstore(KPRE + row * HDIM + QC0 + 0, d0 + bkS[0]);
            gstore(KPRE + row * HDIM + QC0 + 1, d1 + bkS[1]);
            gstore(KPRE + row * HDIM + QC0 + 2, d2 + bkS[2]);
            gstore(KPRE + row * HDIM + QC0 + 3, d3 + bkS[3]);
          }
        }
      }
      cbar(flags, cg, ++ph);
    }
  }
}

extern "C" void kernel_launch(void* const* d_in, const int* in_sizes, int n_in,
                              void* d_out, int out_size, void* d_ws, size_t ws_size,
                              hipStream_t stream) {
  (void)in_sizes; (void)n_in; (void)out_size; (void)ws_size;
  const float* X     = (const float*)d_in[0];
  const float* Wp    = (const float*)d_in[3];
  const float* bp    = (const float*)d_in[4];
  const float* lns   = (const float*)d_in[5];
  const float* lnb   = (const float*)d_in[6];
  const float* Wq    = (const float*)d_in[7];
  const float* bq    = (const float*)d_in[8];
  const float* lnqs  = (const float*)d_in[9];
  const float* lnqb  = (const float*)d_in[10];
  const float* Wk    = (const float*)d_in[11];
  const float* bk    = (const float*)d_in[12];
  const float* lnks  = (const float*)d_in[13];
  const float* lnkb  = (const float*)d_in[14];
  const float* Wbeta = (const float*)d_in[15];
  const float* bbeta = (const float*)d_in[16];
  const float* W1    = (const float*)d_in[17];
  const float* b1    = (const float*)d_in[18];
  const float* W2    = (const float*)d_in[19];
  const float* b2    = (const float*)d_in[20];

  float* out       = (float*)d_out;
  float* out_xp    = out;
  float* out_mem   = out + (size_t)T_LEN * BATCH * HDIM;
  float* out_probs = out_mem + (size_t)T_LEN * BATCH * NS * HDIM;
  float* ws        = (float*)d_ws;

  hipLaunchKernelGGL(init_ctrl, dim3(4), dim3(256), 0, stream, (int*)d_ws);
  hipLaunchKernelGGL(xp_kernel, dim3(1024), dim3(256), 0, stream, X, Wp, bp, lns, lnb, out_xp);
  hipLaunchKernelGGL(omr_main, dim3(256), dim3(NTHR), 0, stream,
                     out_xp, Wq, bq, lnqs, lnqb, Wk, bk, lnks, lnkb, Wbeta, bbeta,
                     W1, b1, W2, b2, lns, lnb, out_mem, out_probs, ws);
}